// Round 14
// baseline (126.221 us; speedup 1.0000x reference)
//
#include <hip/hip_runtime.h>

#define NB 8
#define NS 2048
#define ND 1024
#define NE 8

typedef unsigned short ushort_t;
typedef __attribute__((ext_vector_type(8))) short bf16x8;
typedef __attribute__((ext_vector_type(4))) float f32x4;

__device__ __forceinline__ unsigned short f2bf(float f) {
    union { float f; unsigned int u; } x; x.f = f;
    unsigned int u = x.u + 0x7fffu + ((x.u >> 16) & 1u);
    return (unsigned short)(u >> 16);
}

__device__ __forceinline__ unsigned pk2(float a, float b) {
    return (unsigned)f2bf(a) | ((unsigned)f2bf(b) << 16);
}

__device__ __forceinline__ void gload16(const void* g, void* l) {
    __builtin_amdgcn_global_load_lds(
        (const __attribute__((address_space(1))) unsigned int*)g,
        (__attribute__((address_space(3))) unsigned int*)l, 16, 0, 0);
}

// local top-k gate coefs for one batch row (deterministic tie-break = first index)
__device__ __forceinline__ void coef_local(const float* __restrict__ scores,
                                           int b, int k, float* cf) {
    float s[NE];
#pragma unroll
    for (int e = 0; e < NE; ++e) s[e] = scores[b * NE + e];
    bool sel[NE];
#pragma unroll
    for (int e = 0; e < NE; ++e) sel[e] = false;
    float sum = 0.f;
    for (int j = 0; j < k; ++j) {
        int best = 0; float bv = -3.4e38f;
#pragma unroll
        for (int e = 0; e < NE; ++e)
            if (!sel[e] && s[e] > bv) { bv = s[e]; best = e; }
        sel[best] = true; sum += bv;
    }
    float scale = 1.f / (sum + 1e-8f);
#pragma unroll
    for (int e = 0; e < NE; ++e) cf[e] = sel[e] ? scale * s[e] : 0.f;
}

// ====== fused prep: combine (2048 blk) | bias (32) | routing (1) — NO convert ======
__global__ void prep_kernel(const float* __restrict__ scores,
                            const float* __restrict__ W,
                            const float* __restrict__ eb,
                            const int* __restrict__ kp,
                            ushort_t* __restrict__ wct,
                            float* __restrict__ bias,
                            float* __restrict__ counts) {
    __shared__ float tile[64][65];
    __shared__ int selS[NB][NE];
    int bid = blockIdx.x;
    int t = threadIdx.x;

    if (bid < 2048) {
        int b = bid >> 8;
        int f0 = (bid & 15) * 64, d0 = ((bid >> 4) & 15) * 64;
        float cf[NE];
        coef_local(scores, b, kp[0], cf);
        int lr = t >> 4;
        int lc = (t & 15) * 4;
        float4 acc[4];
#pragma unroll
        for (int it = 0; it < 4; ++it) acc[it] = make_float4(0.f, 0.f, 0.f, 0.f);
#pragma unroll
        for (int e = 0; e < NE; ++e) {
            float c = cf[e];
            if (c != 0.f) {
                const float* We = W + ((size_t)e * ND * ND);
#pragma unroll
                for (int it = 0; it < 4; ++it) {
                    int d = d0 + lr + it * 16;
                    float4 v = *(const float4*)(We + (size_t)d * ND + f0 + lc);
                    acc[it].x += c * v.x; acc[it].y += c * v.y;
                    acc[it].z += c * v.z; acc[it].w += c * v.w;
                }
            }
        }
#pragma unroll
        for (int it = 0; it < 4; ++it) {
            int r = lr + it * 16;
            tile[r][lc + 0] = acc[it].x; tile[r][lc + 1] = acc[it].y;
            tile[r][lc + 2] = acc[it].z; tile[r][lc + 3] = acc[it].w;
        }
        __syncthreads();
        int dl = t & 63;
        int frow = t >> 6;
        ushort_t* dst = wct + (size_t)b * ND * ND + (size_t)f0 * ND + d0 + dl;
#pragma unroll
        for (int it = 0; it < 16; ++it) {
            int f = frow + it * 4;
            dst[(size_t)f * ND] = f2bf(tile[dl][f]);
        }
    } else if (bid < 2080) {
        int i = bid - 2048;
        int b = i >> 2, f = (i & 3) * 256 + t;
        float cf[NE];
        coef_local(scores, b, kp[0], cf);
        float acc = 0.f;
#pragma unroll
        for (int e = 0; e < NE; ++e)
            if (cf[e] != 0.f) acc += cf[e] * eb[e * ND + f];
        bias[b * ND + f] = acc;
    } else {
        int k = kp[0];
        if (t < NB) {
            float s[NE];
#pragma unroll
            for (int e = 0; e < NE; ++e) s[e] = scores[t * NE + e];
            bool sel[NE];
#pragma unroll
            for (int e = 0; e < NE; ++e) sel[e] = false;
            for (int j = 0; j < k; ++j) {
                int best = 0; float bv = -3.4e38f;
#pragma unroll
                for (int e = 0; e < NE; ++e)
                    if (!sel[e] && s[e] > bv) { bv = s[e]; best = e; }
                sel[best] = true;
            }
#pragma unroll
            for (int e = 0; e < NE; ++e) selS[t][e] = sel[e] ? 1 : 0;
        }
        __syncthreads();
        if (t < NE) {
            int c = 0;
#pragma unroll
            for (int b = 0; b < NB; ++b) c += selS[b][t];
            counts[t] = (float)c;
        }
    }
}

// ====== producer-consumer GEMM: 128x128, BK=32, 6 waves (4 MFMA + 2 staging) ======
// Consumer waves NEVER wait on vmcnt; all staging drains sit on producer waves.
// A is cast fp32->bf16 by producers in-kernel (convert kernel deleted).
// 32 KiB LDS, 2 blocks/CU. R9's HW-verified 0-conflict swizzle involution.
__global__ __launch_bounds__(384, 4) void gemm_kernel(const float* __restrict__ x,
                                                      const ushort_t* __restrict__ wct,
                                                      const float* __restrict__ bias,
                                                      float* __restrict__ out) {
    __shared__ ushort_t lA[2][128 * 32];   // 8 KiB each
    __shared__ ushort_t lB[2][128 * 32];

    int bid = blockIdx.x;
    int b = bid & 7;                 // batch -> XCD (round-robin % 8)
    int tile = bid >> 3;             // 0..127
    int m0 = (tile >> 3) * 128;      // 16 M-tiles
    int n0 = (tile & 7) * 128;       // 8 N-tiles

    int t = threadIdx.x, lane = t & 63, wave = t >> 6;
    const int NT = ND / 32;          // 32 K-tiles

    if (wave < 4) {
        // ================= CONSUMER: MFMA only, no vmem waits =================
        int wm = wave >> 1, wn = wave & 1;      // 2x2 grid, wave tile 64x64
        int fr = lane & 15, fq = lane >> 4;
        int swzb = (fq ^ ((fr >> 1) & 3)) * 16;
        int aoff[4], boff[4];
#pragma unroll
        for (int mi = 0; mi < 4; ++mi) aoff[mi] = (wm * 64 + mi * 16 + fr) * 64 + swzb;
#pragma unroll
        for (int nj = 0; nj < 4; ++nj) boff[nj] = (wn * 64 + nj * 16 + fr) * 64 + swzb;

        f32x4 acc[4][4];
#pragma unroll
        for (int i = 0; i < 4; ++i)
#pragma unroll
            for (int j = 0; j < 4; ++j) acc[i][j] = (f32x4){0.f, 0.f, 0.f, 0.f};

        asm volatile("" ::: "memory");
        __builtin_amdgcn_s_barrier();            // prologue barrier
        asm volatile("" ::: "memory");

        for (int kt = 0; kt < NT; ++kt) {
            const char* pA = (const char*)&lA[kt & 1][0];
            const char* pB = (const char*)&lB[kt & 1][0];
            bf16x8 af[4], bf[4];
#pragma unroll
            for (int nj = 0; nj < 4; ++nj) bf[nj] = *(const bf16x8*)(pB + boff[nj]);
#pragma unroll
            for (int mi = 0; mi < 4; ++mi) af[mi] = *(const bf16x8*)(pA + aoff[mi]);
            __builtin_amdgcn_s_setprio(1);
#pragma unroll
            for (int mi = 0; mi < 4; ++mi)
#pragma unroll
                for (int nj = 0; nj < 4; ++nj)
                    acc[mi][nj] = __builtin_amdgcn_mfma_f32_16x16x32_bf16(af[mi], bf[nj], acc[mi][nj], 0, 0, 0);
            __builtin_amdgcn_s_setprio(0);
            if (kt + 1 < NT) {
                asm volatile("s_waitcnt lgkmcnt(0)" ::: "memory");  // own reads done; fence
                __builtin_amdgcn_s_barrier();
                asm volatile("" ::: "memory");
            }
        }

        // ---- epilogue: bias + fp32 store ----
        const float* bs = bias + b * ND;
        float* O = out + ((size_t)b * NS * ND);
#pragma unroll
        for (int mi = 0; mi < 4; ++mi) {
            int row = m0 + wm * 64 + mi * 16 + fq * 4;
#pragma unroll
            for (int nj = 0; nj < 4; ++nj) {
                int col = n0 + wn * 64 + nj * 16 + fr;
                float bv = bs[col];
                f32x4 v = acc[mi][nj];
#pragma unroll
                for (int r = 0; r < 4; ++r)
                    O[(size_t)(row + r) * ND + col] = v[r] + bv;
            }
        }
    } else {
        // ================= PRODUCER: all staging (A fp32->bf16, B DMA) =================
        int p = t - 256;                         // 0..127 -> A row
        int pw = wave - 4;                       // 0,1
        const float* xA = x + (size_t)b * NS * ND + (size_t)(m0 + p) * ND;
        int wsw = (p >> 1) & 3;                  // A write swizzle (read involution)
        // B source: pre-swizzled; (row>>1)&3 == (lane>>3)&3, invariant across instrs
        int brow = pw * 64 + (lane >> 2);
        int slotB = (lane & 3) ^ ((lane >> 3) & 3);
        const ushort_t* sB = wct + (size_t)b * ND * ND + (size_t)(n0 + brow) * ND + slotB * 8;

        float4 r[8];
#define LOADA(kt) do { \
    const float4* xp = (const float4*)(xA + (kt) * 32); \
    _Pragma("unroll") \
    for (int j = 0; j < 8; ++j) r[j] = xp[j]; \
} while (0)
#define GLB(kt, buf) do { \
    _Pragma("unroll") \
    for (int i = 0; i < 4; ++i) \
        gload16(sB + (kt) * 32 + (size_t)(i * 16) * ND, &lB[buf][(pw * 64 + i * 16) * 32]); \
} while (0)
#define CVTW(buf) do { \
    _Pragma("unroll") \
    for (int j = 0; j < 4; ++j) { \
        uint4 o; \
        o.x = pk2(r[2 * j].x, r[2 * j].y);         o.y = pk2(r[2 * j].z, r[2 * j].w); \
        o.z = pk2(r[2 * j + 1].x, r[2 * j + 1].y); o.w = pk2(r[2 * j + 1].z, r[2 * j + 1].w); \
        *(uint4*)(&lA[buf][p * 32 + ((j ^ wsw) * 8)]) = o; \
    } \
} while (0)

        // ---- prologue: tile 0 -> buf 0; A(1) regs in flight ----
        LOADA(0);
        GLB(0, 0);
        asm volatile("s_waitcnt vmcnt(4)" ::: "memory");   // A(0) regs landed
        CVTW(0);
        asm volatile("s_waitcnt vmcnt(0)" ::: "memory");   // B(0) in LDS
        asm volatile("s_waitcnt lgkmcnt(0)" ::: "memory"); // A writes drained
        LOADA(1);                                          // A(1) -> regs (8 outstanding)
        __builtin_amdgcn_s_barrier();

        for (int kt = 0; kt < NT; ++kt) {
            if (kt + 1 < NT) {
                int nb = (kt + 1) & 1;
                GLB(kt + 1, nb);                                   // 4 B gloads (12 out)
                asm volatile("s_waitcnt vmcnt(4)" ::: "memory");   // A(t+1) regs landed
                CVTW(nb);
                asm volatile("s_waitcnt vmcnt(0)" ::: "memory");   // B(t+1) in LDS
                asm volatile("s_waitcnt lgkmcnt(0)" ::: "memory"); // A writes drained
                if (kt + 2 < NT) LOADA(kt + 2);                    // full-tile runway
                __builtin_amdgcn_s_barrier();
            }
        }
#undef LOADA
#undef GLB
#undef CVTW
    }
}

extern "C" void kernel_launch(void* const* d_in, const int* in_sizes, int n_in,
                              void* d_out, int out_size, void* d_ws, size_t ws_size,
                              hipStream_t stream) {
    const float* x      = (const float*)d_in[0];
    const float* scores = (const float*)d_in[1];
    const float* Wx     = (const float*)d_in[2];
    const float* eb     = (const float*)d_in[3];
    const int*   kp     = (const int*)d_in[4];
    float* out = (float*)d_out;
    char* ws = (char*)d_ws;

    float*    bias  = (float*)(ws + 1024);
    ushort_t* wct   = (ushort_t*)(ws + 65536);
    float*    counts = out + (size_t)NB * NS * ND;

    prep_kernel<<<2081, 256, 0, stream>>>(scores, Wx, eb, kp, wct, bias, counts);
    gemm_kernel<<<1024, 384, 0, stream>>>(x, wct, bias, out);
}

// Round 15
// 69.781 us; speedup vs baseline: 1.8088x; 1.8088x over previous
//
#include <hip/hip_runtime.h>

#define NB 8
#define NS 2048
#define ND 1024
#define NE 8

typedef unsigned short ushort_t;
typedef __attribute__((ext_vector_type(8))) short bf16x8;
typedef __attribute__((ext_vector_type(4))) float f32x4;

__device__ __forceinline__ unsigned short f2bf(float f) {
    union { float f; unsigned int u; } x; x.f = f;
    unsigned int u = x.u + 0x7fffu + ((x.u >> 16) & 1u);
    return (unsigned short)(u >> 16);
}

__device__ __forceinline__ void gload16(const void* g, void* l) {
    __builtin_amdgcn_global_load_lds(
        (const __attribute__((address_space(1))) unsigned int*)g,
        (__attribute__((address_space(3))) unsigned int*)l, 16, 0, 0);
}

// local top-k gate coefs for one batch row (deterministic tie-break = first index)
__device__ __forceinline__ void coef_local(const float* __restrict__ scores,
                                           int b, int k, float* cf) {
    float s[NE];
#pragma unroll
    for (int e = 0; e < NE; ++e) s[e] = scores[b * NE + e];
    bool sel[NE];
#pragma unroll
    for (int e = 0; e < NE; ++e) sel[e] = false;
    float sum = 0.f;
    for (int j = 0; j < k; ++j) {
        int best = 0; float bv = -3.4e38f;
#pragma unroll
        for (int e = 0; e < NE; ++e)
            if (!sel[e] && s[e] > bv) { bv = s[e]; best = e; }
        sel[best] = true; sum += bv;
    }
    float scale = 1.f / (sum + 1e-8f);
#pragma unroll
    for (int e = 0; e < NE; ++e) cf[e] = sel[e] ? scale * s[e] : 0.f;
}

// ====== fused prep: combine (2048 blk) | convert (8192 blk) | bias (32) | routing (1) ======
__global__ void prep_kernel(const float* __restrict__ x,
                            const float* __restrict__ scores,
                            const float* __restrict__ W,
                            const float* __restrict__ eb,
                            const int* __restrict__ kp,
                            ushort_t* __restrict__ xb,
                            ushort_t* __restrict__ wct,
                            float* __restrict__ bias,
                            float* __restrict__ counts) {
    __shared__ float tile[64][65];
    __shared__ int selS[NB][NE];
    int bid = blockIdx.x;
    int t = threadIdx.x;

    if (bid < 2048) {
        int b = bid >> 8;
        int f0 = (bid & 15) * 64, d0 = ((bid >> 4) & 15) * 64;
        float cf[NE];
        coef_local(scores, b, kp[0], cf);
        int lr = t >> 4;
        int lc = (t & 15) * 4;
        float4 acc[4];
#pragma unroll
        for (int it = 0; it < 4; ++it) acc[it] = make_float4(0.f, 0.f, 0.f, 0.f);
#pragma unroll
        for (int e = 0; e < NE; ++e) {
            float c = cf[e];
            if (c != 0.f) {
                const float* We = W + ((size_t)e * ND * ND);
#pragma unroll
                for (int it = 0; it < 4; ++it) {
                    int d = d0 + lr + it * 16;
                    float4 v = *(const float4*)(We + (size_t)d * ND + f0 + lc);
                    acc[it].x += c * v.x; acc[it].y += c * v.y;
                    acc[it].z += c * v.z; acc[it].w += c * v.w;
                }
            }
        }
#pragma unroll
        for (int it = 0; it < 4; ++it) {
            int r = lr + it * 16;
            tile[r][lc + 0] = acc[it].x; tile[r][lc + 1] = acc[it].y;
            tile[r][lc + 2] = acc[it].z; tile[r][lc + 3] = acc[it].w;
        }
        __syncthreads();
        int dl = t & 63;
        int frow = t >> 6;
        ushort_t* dst = wct + (size_t)b * ND * ND + (size_t)f0 * ND + d0 + dl;
#pragma unroll
        for (int it = 0; it < 16; ++it) {
            int f = frow + it * 4;
            dst[(size_t)f * ND] = f2bf(tile[dl][f]);
        }
    } else if (bid < 10240) {
        size_t i = (size_t)(bid - 2048) * 256 + t;
        const float4* p = (const float4*)x + 2 * i;
        float4 a = p[0], b = p[1];
        uint4 o;
        o.x = (unsigned)f2bf(a.x) | ((unsigned)f2bf(a.y) << 16);
        o.y = (unsigned)f2bf(a.z) | ((unsigned)f2bf(a.w) << 16);
        o.z = (unsigned)f2bf(b.x) | ((unsigned)f2bf(b.y) << 16);
        o.w = (unsigned)f2bf(b.z) | ((unsigned)f2bf(b.w) << 16);
        ((uint4*)xb)[i] = o;
    } else if (bid < 10272) {
        int i = bid - 10240;
        int b = i >> 2, f = (i & 3) * 256 + t;
        float cf[NE];
        coef_local(scores, b, kp[0], cf);
        float acc = 0.f;
#pragma unroll
        for (int e = 0; e < NE; ++e)
            if (cf[e] != 0.f) acc += cf[e] * eb[e * ND + f];
        bias[b * ND + f] = acc;
    } else {
        int k = kp[0];
        if (t < NB) {
            float s[NE];
#pragma unroll
            for (int e = 0; e < NE; ++e) s[e] = scores[t * NE + e];
            bool sel[NE];
#pragma unroll
            for (int e = 0; e < NE; ++e) sel[e] = false;
            for (int j = 0; j < k; ++j) {
                int best = 0; float bv = -3.4e38f;
#pragma unroll
                for (int e = 0; e < NE; ++e)
                    if (!sel[e] && s[e] > bv) { bv = s[e]; best = e; }
                sel[best] = true;
            }
#pragma unroll
            for (int e = 0; e < NE; ++e) selS[t][e] = sel[e] ? 1 : 0;
        }
        __syncthreads();
        if (t < NE) {
            int c = 0;
#pragma unroll
            for (int b = 0; b < NB; ++b) c += selS[b][t];
            counts[t] = (float)c;
        }
    }
}

// ====== R9 structure (256x128, BK=32, 3-buf, 2 blocks/CU, counted vmcnt(3)) ======
// ONE CHANGE vs R9: no manual lgkmcnt/sched_barrier between LDS frag reads and
// MFMA — compiler emits fine-grained lgkmcnt(N) so MFMAs overlap read latency
// (m97 behavior; Common-mistake #5: order-pinning defeats compiler scheduling).
__global__ __launch_bounds__(512, 4) void gemm_kernel(const ushort_t* __restrict__ xb,
                                                      const ushort_t* __restrict__ wct,
                                                      const float* __restrict__ bias,
                                                      float* __restrict__ out) {
    __shared__ ushort_t ldsA[3][256 * 32];   // 48 KiB
    __shared__ ushort_t ldsB[3][128 * 32];   // 24 KiB

    int bid = blockIdx.x;
    int b = bid & 7;                 // batch -> XCD (round-robin % 8)
    int tile = bid >> 3;             // 0..63
    int m0 = (tile >> 3) * 256;      // 8 M-tiles
    int n0 = (tile & 7) * 128;       // 8 N-tiles
    const ushort_t* A  = xb  + ((size_t)b * NS * ND) + (size_t)m0 * ND;
    const ushort_t* Bt = wct + ((size_t)b * ND * ND) + (size_t)n0 * ND;

    int t = threadIdx.x, lane = t & 63, wave = t >> 6;
    int wm = wave >> 1, wn = wave & 1;          // 4 x 2 wave grid, wave tile 64x64
    int fr = lane & 15, fq = lane >> 4;

    // ---- staging source (pre-swizzled: slot ^= (row>>1)&3; LDS dest linear) ----
    int srow = t >> 2;                               // 0..127
    int slotg = (t & 3) ^ ((srow >> 1) & 3);
    const ushort_t* sA = A  + (size_t)srow * ND + slotg * 8;
    const ushort_t* sB = Bt + (size_t)srow * ND + slotg * 8;
    int ldst = t * 8;                                // ushort offset; A instr1 at +4096

    // ---- read-side fragment byte offsets (HW-verified 0-conflict swizzle) ----
    int swzb = (fq ^ ((fr >> 1) & 3)) * 16;
    int aoff[4], boff[4];
#pragma unroll
    for (int mi = 0; mi < 4; ++mi) aoff[mi] = (wm * 64 + mi * 16 + fr) * 64 + swzb;
#pragma unroll
    for (int nj = 0; nj < 4; ++nj) boff[nj] = (wn * 64 + nj * 16 + fr) * 64 + swzb;

    f32x4 acc[4][4];
#pragma unroll
    for (int i = 0; i < 4; ++i)
#pragma unroll
        for (int j = 0; j < 4; ++j) acc[i][j] = (f32x4){0.f, 0.f, 0.f, 0.f};

    const int NT = ND / 32;   // 32 K-tiles

#define STAGE(kt, buf) do { \
    gload16(sA + (kt) * 32,            &ldsA[buf][ldst]); \
    gload16(sA + (kt) * 32 + 128 * ND, &ldsA[buf][4096 + ldst]); \
    gload16(sB + (kt) * 32,            &ldsB[buf][ldst]); \
} while (0)

    // ---- prologue: stage tiles 0,1 -> bufs 0,1 ----
    STAGE(0, 0);
    STAGE(1, 1);
    asm volatile("s_waitcnt vmcnt(3)" ::: "memory");   // tile 0 landed
    __builtin_amdgcn_s_barrier();

    int cur = 0;
    for (int kt = 0; kt < NT; ++kt) {
        const char* lA = (const char*)&ldsA[cur][0];
        const char* lB = (const char*)&ldsB[cur][0];
        int sq = cur + 2; if (sq >= 3) sq -= 3;        // buffer for tile kt+2

        // stage tile kt+2 FIRST (DMA in flight across this tile's compute + barrier)
        if (kt + 2 < NT) STAGE(kt + 2, sq);

        // frag reads + MFMA: COMPILER-SCHEDULED (fine-grained lgkmcnt interleave)
        bf16x8 af[4], bf[4];
#pragma unroll
        for (int nj = 0; nj < 4; ++nj) bf[nj] = *(const bf16x8*)(lB + boff[nj]);
#pragma unroll
        for (int mi = 0; mi < 4; ++mi) af[mi] = *(const bf16x8*)(lA + aoff[mi]);
        __builtin_amdgcn_s_setprio(1);
#pragma unroll
        for (int mi = 0; mi < 4; ++mi)
#pragma unroll
            for (int nj = 0; nj < 4; ++nj)
                acc[mi][nj] = __builtin_amdgcn_mfma_f32_16x16x32_bf16(af[mi], bf[nj], acc[mi][nj], 0, 0, 0);
        __builtin_amdgcn_s_setprio(0);
        // counted wait (memory clobber also fences next-iter reads below barrier):
        // tile kt+1's 3 loads retired; kt+2's 3 stay in flight
        if (kt + 2 < NT) {
            asm volatile("s_waitcnt vmcnt(3)" ::: "memory");
        } else if (kt + 1 < NT) {
            asm volatile("s_waitcnt vmcnt(0)" ::: "memory");
        }
        if (kt + 1 < NT) __builtin_amdgcn_s_barrier();
        cur += 1; if (cur == 3) cur = 0;
    }

#undef STAGE

    // ---- epilogue: bias + fp32 store ----
    const float* bs = bias + b * ND;
    float* O = out + ((size_t)b * NS * ND);
#pragma unroll
    for (int mi = 0; mi < 4; ++mi) {
        int row = m0 + wm * 64 + mi * 16 + fq * 4;
#pragma unroll
        for (int nj = 0; nj < 4; ++nj) {
            int col = n0 + wn * 64 + nj * 16 + fr;
            float bv = bs[col];
            f32x4 v = acc[mi][nj];
#pragma unroll
            for (int r = 0; r < 4; ++r)
                O[(size_t)(row + r) * ND + col] = v[r] + bv;
        }
    }
}

extern "C" void kernel_launch(void* const* d_in, const int* in_sizes, int n_in,
                              void* d_out, int out_size, void* d_ws, size_t ws_size,
                              hipStream_t stream) {
    const float* x      = (const float*)d_in[0];
    const float* scores = (const float*)d_in[1];
    const float* Wx     = (const float*)d_in[2];
    const float* eb     = (const float*)d_in[3];
    const int*   kp     = (const int*)d_in[4];
    float* out = (float*)d_out;
    char* ws = (char*)d_ws;

    float*    bias  = (float*)(ws + 1024);
    ushort_t* xbuf  = (ushort_t*)(ws + 65536);
    ushort_t* wct   = (ushort_t*)(ws + 65536 + (size_t)NB * NS * ND * 2);
    float*    counts = out + (size_t)NB * NS * ND;

    prep_kernel<<<10273, 256, 0, stream>>>(x, scores, Wx, eb, kp, xbuf, wct, bias, counts);
    gemm_kernel<<<512, 512, 0, stream>>>(xbuf, wct, bias, out);
}